// Round 5
// baseline (132.355 us; speedup 1.0000x reference)
//
#include <hip/hip_runtime.h>
#include <stdint.h>

// out[b,o] = x@W - 0.5*(||x_b||^2 + ||w_o||^2)
// x [2048][1024] f32, W [1024][4096] f32, out [2048][4096] f32
#define BATCH 2048
#define DIN   1024
#define DOUT  4096

// ---------- helpers ----------

__device__ __forceinline__ ushort f2bf(float f) {
    uint32_t u = __float_as_uint(f);
    u += 0x7fffu + ((u >> 16) & 1u);
    return (ushort)(u >> 16);
}

// async global->LDS, 16B/lane; LDS dest is wave-uniform base + lane*16 (m97/m104)
__device__ __forceinline__ void async_copy16(const void* gsrc, void* ldst) {
    __builtin_amdgcn_global_load_lds(
        reinterpret_cast<uint32_t __attribute__((address_space(1)))*>(
            reinterpret_cast<uintptr_t>(gsrc)),
        reinterpret_cast<uint32_t __attribute__((address_space(3)))*>(
            reinterpret_cast<uintptr_t>(ldst)),
        16, 0, 0);
}

typedef __bf16 bf16x8 __attribute__((ext_vector_type(8)));
typedef float  f32x4  __attribute__((ext_vector_type(4)));

// ---------- fused prep (one dispatch) ----------
// Blocks [0,256): transpose W chunk -> wbt bf16 + K-partial col sums wsqp.
// Blocks [256,384): cast x -> bf16 + row sums xsq (wave-per-row, 4 rows/wave).
__global__ __launch_bounds__(256) void prep_fused(const float* __restrict__ x,
                                                  const float* __restrict__ W,
                                                  ushort* __restrict__ xb,
                                                  float* __restrict__ xsq,
                                                  ushort* __restrict__ wbt,
                                                  float* __restrict__ wsqp) {
    __shared__ float tile[64][65];
    const int b = blockIdx.x;
    if (b < 256) {
        const int o0 = (b >> 2) * 64;
        const int jb = b & 3;  // K-chunk 0..3
        const int tx = threadIdx.x & 63;
        const int ty = threadIdx.x >> 6;
        float ssq = 0.f;
        for (int sub = 0; sub < 4; ++sub) {
            const int i0 = jb * 256 + sub * 64;
            if (sub) __syncthreads();
            #pragma unroll
            for (int r = ty; r < 64; r += 4) {
                const float v = W[(size_t)(i0 + r) * DOUT + o0 + tx];
                tile[r][tx] = v;
                ssq += v * v;
            }
            __syncthreads();
            #pragma unroll
            for (int r = ty; r < 64; r += 4)
                wbt[(size_t)(o0 + r) * DIN + i0 + tx] = f2bf(tile[tx][r]);
        }
        __syncthreads();
        tile[ty][tx] = ssq;
        __syncthreads();
        if (ty == 0)
            wsqp[(size_t)jb * DOUT + o0 + tx] =
                tile[0][tx] + tile[1][tx] + tile[2][tx] + tile[3][tx];
    } else {
        const int blk  = b - 256;             // 0..127, 16 rows each
        const int wv   = threadIdx.x >> 6;
        const int lane = threadIdx.x & 63;
        #pragma unroll
        for (int rr = 0; rr < 4; ++rr) {
            const int row = blk * 16 + wv * 4 + rr;
            const float4* src = (const float4*)(x + (size_t)row * DIN);
            ushort4* dst = (ushort4*)(xb + (size_t)row * DIN);
            float s = 0.f;
            #pragma unroll
            for (int c = 0; c < 4; ++c) {
                const float4 v = src[c * 64 + lane];
                ushort4 pk;
                pk.x = f2bf(v.x); pk.y = f2bf(v.y);
                pk.z = f2bf(v.z); pk.w = f2bf(v.w);
                dst[c * 64 + lane] = pk;
                s += v.x * v.x + v.y * v.y + v.z * v.z + v.w * v.w;
            }
            #pragma unroll
            for (int off = 32; off > 0; off >>= 1) s += __shfl_down(s, off);
            if (lane == 0) xsq[row] = s;
        }
    }
}

// ---------- GEMM + epilogue ----------
// A = xb staged via global_load_lds (the slow ~22 B/cyc/CU pipe -> A only).
// B = wbt read as per-lane 16 B fragments DIRECTLY from global (dwordx4,
// 64 B-segment coalescing, L2-reused across m-blocks), double-banked and
// prefetched one BK=64 half ahead so latency hides behind the MFMA phase.
// 128x128 tile, BK=64, 4 waves (2x2), 4x4 16x16x32 MFMA per 32-k window.
// LDS swizzle for sA (per 128 B row, 8 chunks): chunk c at (c + row) & 7.
#define BM 128
#define BN 128
#define BK 64

__global__ __launch_bounds__(256, 2) void gemm_bt_epi(
    const ushort* __restrict__ A,
    const ushort* __restrict__ Bt,
    const float* __restrict__ xsq,
    const float* __restrict__ wsqp,
    float* __restrict__ out) {
    __shared__ __align__(16) ushort sA[BM * BK];  // 16 KiB (A only)

    const int tid  = threadIdx.x;
    const int wv   = tid >> 6;
    const int lane = tid & 63;
    const int wr = wv >> 1, wc = wv & 1;

    // XCD-aware decode (bijective on 512 blocks); harmless if mapping shifts
    const int bid  = blockIdx.x;
    const int xcd  = bid & 7;
    const int slot = bid >> 3;
    const int nb   = xcd * 4 + (slot & 3);
    const int mb   = slot >> 2;
    const int m0 = mb * BM;
    const int n0 = nb * BN;

    // A staging: wave wv fills rows [wv*32, +32), 4 insts/K-tile.
    // Inst q: lane l -> row wv*32 + q*8 + (l>>3), stored chunk pos l&7,
    // global chunk c = ((l&7) - (l>>3)) & 7.
    const int st_row = wv * 32 + (lane >> 3);
    const int st_c   = ((((lane & 7) - (lane >> 3)) & 7)) * 8;
    const ushort* agp = A + (size_t)(m0 + st_row) * DIN + st_c;

    // B fragment base: lane holds Bt[n0 + wc*64 + ni*16 + (lane&15)][k..k+8)
    const ushort* bq = Bt + (size_t)(n0 + wc * 64 + (lane & 15)) * DIN
                          + ((lane >> 4) * 8);

    f32x4 acc[4][4] = {};

    // A fragment geometry: row m = wr*64 + (lane&15) + i*16; wanted chunk for
    // window kk is c = (lane>>4) + 4*kk, stored at p = (c + (lane&7)) & 7.
    const int a_row = wr * 64 + (lane & 15);
    int kpos[2];
    #pragma unroll
    for (int kk = 0; kk < 2; ++kk)
        kpos[kk] = ((((lane >> 4) + 4 * kk + (lane & 7)) & 7)) * 8;

    bf16x8 b0[2][4], b1[2][4];
    #pragma unroll
    for (int kk = 0; kk < 2; ++kk)
        #pragma unroll
        for (int ni = 0; ni < 4; ++ni)
            b0[kk][ni] = *(const bf16x8*)(bq + (size_t)ni * 16 * DIN + kk * 32);

    for (int kt = 0; kt < DIN; kt += 2 * BK) {
        // ---- half 1: stage A(kt), compute with b0, prefetch b1 @ kt+BK ----
        __syncthreads();  // sA reuse guard
        #pragma unroll
        for (int q = 0; q < 4; ++q)
            async_copy16(agp + (size_t)q * 8 * DIN + kt, &sA[wv * 2048 + q * 512]);
        __syncthreads();  // staging visible

        {
            const int ktn = kt + BK;  // <= DIN-BK, always valid
            #pragma unroll
            for (int kk = 0; kk < 2; ++kk)
                #pragma unroll
                for (int ni = 0; ni < 4; ++ni)
                    b1[kk][ni] = *(const bf16x8*)(bq + (size_t)ni * 16 * DIN +
                                                  ktn + kk * 32);
        }
        #pragma unroll
        for (int kk = 0; kk < 2; ++kk) {
            bf16x8 fa[4];
            #pragma unroll
            for (int i = 0; i < 4; ++i)
                fa[i] = *(const bf16x8*)&sA[(a_row + i * 16) * BK + kpos[kk]];
            #pragma unroll
            for (int mi = 0; mi < 4; ++mi)
                #pragma unroll
                for (int ni = 0; ni < 4; ++ni)
                    acc[mi][ni] = __builtin_amdgcn_mfma_f32_16x16x32_bf16(
                        fa[mi], b0[kk][ni], acc[mi][ni], 0, 0, 0);
        }

        // ---- half 2: stage A(kt+BK), compute with b1, prefetch b0 ----
        __syncthreads();
        #pragma unroll
        for (int q = 0; q < 4; ++q)
            async_copy16(agp + (size_t)q * 8 * DIN + kt + BK,
                         &sA[wv * 2048 + q * 512]);
        __syncthreads();

        {
            const int ktn = (kt + 2 * BK < DIN) ? kt + 2 * BK : 0;  // clamp tail
            #pragma unroll
            for (int kk = 0; kk < 2; ++kk)
                #pragma unroll
                for (int ni = 0; ni < 4; ++ni)
                    b0[kk][ni] = *(const bf16x8*)(bq + (size_t)ni * 16 * DIN +
                                                  ktn + kk * 32);
        }
        #pragma unroll
        for (int kk = 0; kk < 2; ++kk) {
            bf16x8 fa[4];
            #pragma unroll
            for (int i = 0; i < 4; ++i)
                fa[i] = *(const bf16x8*)&sA[(a_row + i * 16) * BK + kpos[kk]];
            #pragma unroll
            for (int mi = 0; mi < 4; ++mi)
                #pragma unroll
                for (int ni = 0; ni < 4; ++ni)
                    acc[mi][ni] = __builtin_amdgcn_mfma_f32_16x16x32_bf16(
                        fa[mi], b1[kk][ni], acc[mi][ni], 0, 0, 0);
        }
    }

    // Epilogue. C/D layout (m89/m91): col = lane&15, row = (lane>>4)*4 + r.
    const int er = (lane >> 4) * 4;
    const int ec = lane & 15;
    float wh[4];
    #pragma unroll
    for (int ni = 0; ni < 4; ++ni) {
        const int col = n0 + wc * 64 + ni * 16 + ec;
        wh[ni] = 0.5f * (wsqp[col] + wsqp[DOUT + col] +
                         wsqp[2 * DOUT + col] + wsqp[3 * DOUT + col]);
    }
    #pragma unroll
    for (int mi = 0; mi < 4; ++mi) {
        const int row = m0 + wr * 64 + mi * 16 + er;
        #pragma unroll
        for (int r = 0; r < 4; ++r) {
            const float xh = 0.5f * xsq[row + r];
            #pragma unroll
            for (int ni = 0; ni < 4; ++ni) {
                const int col = n0 + wc * 64 + ni * 16 + ec;
                out[(size_t)(row + r) * DOUT + col] = acc[mi][ni][r] - xh - wh[ni];
            }
        }
    }
}

// ---------- launch ----------

extern "C" void kernel_launch(void* const* d_in, const int* in_sizes, int n_in,
                              void* d_out, int out_size, void* d_ws, size_t ws_size,
                              hipStream_t stream) {
    const float* x = (const float*)d_in[0];
    const float* W = (const float*)d_in[1];
    float* out = (float*)d_out;

    // Workspace layout (~12.1 MiB):
    //   [0, 4MiB)             xb   : bf16 x   [2048][1024]
    //   [4MiB, 12MiB)         wbt  : bf16 W^T [4096][1024]
    //   [12MiB, +8KiB)        xsq  : f32 [2048]
    //   [12MiB+32KiB, +64KiB) wsqp : f32 [4][4096] K-partial col sums
    char* ws = (char*)d_ws;
    ushort* xb   = (ushort*)ws;
    ushort* wbt  = (ushort*)(ws + (4u << 20));
    float*  xsq  = (float*)(ws + (12u << 20));
    float*  wsqp = (float*)(ws + (12u << 20) + (32u << 10));

    prep_fused<<<384, 256, 0, stream>>>(x, W, xb, xsq, wbt, wsqp);
    gemm_bt_epi<<<512, 256, 0, stream>>>(xb, wbt, xsq, wsqp, out);
}

// Round 6
// 112.027 us; speedup vs baseline: 1.1815x; 1.1815x over previous
//
#include <hip/hip_runtime.h>
#include <stdint.h>

// out[b,o] = x@W - 0.5*(||x_b||^2 + ||w_o||^2)
// x [2048][1024] f32, W [1024][4096] f32, out [2048][4096] f32
#define BATCH 2048
#define DIN   1024
#define DOUT  4096

// ---------- helpers ----------

__device__ __forceinline__ ushort f2bf(float f) {
    uint32_t u = __float_as_uint(f);
    u += 0x7fffu + ((u >> 16) & 1u);
    return (ushort)(u >> 16);
}

// async global->LDS, 16B/lane; LDS dest is wave-uniform base + lane*16 (m97/m104)
__device__ __forceinline__ void async_copy16(const void* gsrc, void* ldst) {
    __builtin_amdgcn_global_load_lds(
        reinterpret_cast<uint32_t __attribute__((address_space(1)))*>(
            reinterpret_cast<uintptr_t>(gsrc)),
        reinterpret_cast<uint32_t __attribute__((address_space(3)))*>(
            reinterpret_cast<uintptr_t>(ldst)),
        16, 0, 0);
}

typedef __bf16 bf16x8 __attribute__((ext_vector_type(8)));
typedef float  f32x4  __attribute__((ext_vector_type(4)));

// ---------- fused prep (one dispatch) ----------
// Blocks [0,256): transpose W chunk -> wbt bf16 + K-partial col sums wsqp.
// Blocks [256,384): cast x -> bf16 + row sums xsq (wave-per-row, 4 rows/wave).
__global__ __launch_bounds__(256) void prep_fused(const float* __restrict__ x,
                                                  const float* __restrict__ W,
                                                  ushort* __restrict__ xb,
                                                  float* __restrict__ xsq,
                                                  ushort* __restrict__ wbt,
                                                  float* __restrict__ wsqp) {
    __shared__ float tile[64][65];
    const int b = blockIdx.x;
    if (b < 256) {
        const int o0 = (b >> 2) * 64;
        const int jb = b & 3;  // K-chunk 0..3
        const int tx = threadIdx.x & 63;
        const int ty = threadIdx.x >> 6;
        float ssq = 0.f;
        for (int sub = 0; sub < 4; ++sub) {
            const int i0 = jb * 256 + sub * 64;
            if (sub) __syncthreads();
            #pragma unroll
            for (int r = ty; r < 64; r += 4) {   // coalesced read of W rows
                const float v = W[(size_t)(i0 + r) * DOUT + o0 + tx];
                tile[r][tx] = v;
                ssq += v * v;
            }
            __syncthreads();
            // ushort4 stores: lane -> (o-row, 4-elem i-chunk). LDS banks:
            // word (ch*4+j)*65 + o -> (4ch+o+65j) mod 32 = 2-way only = free.
            #pragma unroll
            for (int p = 0; p < 4; ++p) {
                const int o  = p * 16 + (threadIdx.x >> 4);
                const int ch = threadIdx.x & 15;
                ushort4 pk;
                pk.x = f2bf(tile[ch * 4 + 0][o]);
                pk.y = f2bf(tile[ch * 4 + 1][o]);
                pk.z = f2bf(tile[ch * 4 + 2][o]);
                pk.w = f2bf(tile[ch * 4 + 3][o]);
                *(ushort4*)(wbt + (size_t)(o0 + o) * DIN + i0 + ch * 4) = pk;
            }
        }
        __syncthreads();
        tile[ty][tx] = ssq;
        __syncthreads();
        if (ty == 0)
            wsqp[(size_t)jb * DOUT + o0 + tx] =
                tile[0][tx] + tile[1][tx] + tile[2][tx] + tile[3][tx];
    } else {
        const int blk  = b - 256;             // 0..127, 16 rows each
        const int wv   = threadIdx.x >> 6;
        const int lane = threadIdx.x & 63;
        #pragma unroll
        for (int rr = 0; rr < 4; ++rr) {
            const int row = blk * 16 + wv * 4 + rr;
            const float4* src = (const float4*)(x + (size_t)row * DIN);
            ushort4* dst = (ushort4*)(xb + (size_t)row * DIN);
            float s = 0.f;
            #pragma unroll
            for (int c = 0; c < 4; ++c) {
                const float4 v = src[c * 64 + lane];
                ushort4 pk;
                pk.x = f2bf(v.x); pk.y = f2bf(v.y);
                pk.z = f2bf(v.z); pk.w = f2bf(v.w);
                dst[c * 64 + lane] = pk;
                s += v.x * v.x + v.y * v.y + v.z * v.z + v.w * v.w;
            }
            #pragma unroll
            for (int off = 32; off > 0; off >>= 1) s += __shfl_down(s, off);
            if (lane == 0) xsq[row] = s;
        }
    }
}

// ---------- GEMM + epilogue ----------
// A,B both staged via global_load_lds into DOUBLE-BUFFERED LDS (2 x 32 KiB).
// Single barrier per K-iter: next tile's copies issue BEFORE the compute
// phase, so the compiler's vmcnt(0)-before-s_barrier drain is pre-hidden
// behind ~32 MFMA + 16 ds_read_b128. 128x128 tile, BK=64, 4 waves (2x2).
// LDS swizzle (per 128 B row, 8 x 16B chunks): chunk c stored at (c+row)&7
// -> ds_read_b128 hits all 8 bank-groups 2-way = free.
#define BM 128
#define BN 128
#define BK 64

__global__ __launch_bounds__(256, 2) void gemm_bt_epi(
    const ushort* __restrict__ A,
    const ushort* __restrict__ Bt,
    const float* __restrict__ xsq,
    const float* __restrict__ wsqp,
    float* __restrict__ out) {
    __shared__ __align__(16) ushort sA[2 * BM * BK];  // 2 x 16 KiB
    __shared__ __align__(16) ushort sB[2 * BN * BK];  // 2 x 16 KiB

    const int tid  = threadIdx.x;
    const int wv   = tid >> 6;
    const int lane = tid & 63;
    const int wr = wv >> 1, wc = wv & 1;

    // XCD-aware decode (bijective on 512 blocks); neutral but harmless
    const int bid  = blockIdx.x;
    const int xcd  = bid & 7;
    const int slot = bid >> 3;
    const int nb   = xcd * 4 + (slot & 3);
    const int mb   = slot >> 2;
    const int m0 = mb * BM;
    const int n0 = nb * BN;

    // Staging: wave wv fills tile rows [wv*32, +32), 4 insts of 1 KiB per
    // operand. Inst q: lane l -> row wv*32 + q*8 + (l>>3), stored pos l&7,
    // global chunk c = ((l&7) - (l>>3)) & 7.
    const int st_row = wv * 32 + (lane >> 3);
    const int st_c   = ((((lane & 7) - (lane >> 3)) & 7)) * 8;

    const ushort* agp = A  + (size_t)(m0 + st_row) * DIN + st_c;
    const ushort* bgp = Bt + (size_t)(n0 + st_row) * DIN + st_c;

    f32x4 acc[4][4] = {};

    // Fragment geometry: row m = base + (lane&15) + i*16; wanted chunk for
    // 32-k window kk is c = (lane>>4) + 4*kk, stored at p = (c + (lane&7))&7.
    const int a_row = wr * 64 + (lane & 15);
    const int b_row = wc * 64 + (lane & 15);
    int kpos[2];
    #pragma unroll
    for (int kk = 0; kk < 2; ++kk)
        kpos[kk] = ((((lane >> 4) + 4 * kk + (lane & 7)) & 7)) * 8;

    // Prologue: stage tile k=0 into buffer 0
    #pragma unroll
    for (int q = 0; q < 4; ++q)
        async_copy16(agp + (size_t)q * 8 * DIN, &sA[wv * 2048 + q * 512]);
    #pragma unroll
    for (int q = 0; q < 4; ++q)
        async_copy16(bgp + (size_t)q * 8 * DIN, &sB[wv * 2048 + q * 512]);
    __syncthreads();

    int cur = 0;
    for (int kt = 0; kt < DIN; kt += BK) {
        // Issue next tile's staging into the other buffer (no wait here).
        const int ktn = kt + BK;
        if (ktn < DIN) {
            const int nxt = (cur ^ 1) * 8192;
            #pragma unroll
            for (int q = 0; q < 4; ++q)
                async_copy16(agp + (size_t)q * 8 * DIN + ktn,
                             &sA[nxt + wv * 2048 + q * 512]);
            #pragma unroll
            for (int q = 0; q < 4; ++q)
                async_copy16(bgp + (size_t)q * 8 * DIN + ktn,
                             &sB[nxt + wv * 2048 + q * 512]);
        }

        // Compute on current buffer.
        const ushort* cA = &sA[cur * 8192];
        const ushort* cB = &sB[cur * 8192];
        #pragma unroll
        for (int kk = 0; kk < 2; ++kk) {
            bf16x8 fa[4], fb[4];
            #pragma unroll
            for (int i = 0; i < 4; ++i)
                fa[i] = *(const bf16x8*)&cA[(a_row + i * 16) * BK + kpos[kk]];
            #pragma unroll
            for (int i = 0; i < 4; ++i)
                fb[i] = *(const bf16x8*)&cB[(b_row + i * 16) * BK + kpos[kk]];
            #pragma unroll
            for (int mi = 0; mi < 4; ++mi)
                #pragma unroll
                for (int ni = 0; ni < 4; ++ni)
                    acc[mi][ni] = __builtin_amdgcn_mfma_f32_16x16x32_bf16(
                        fa[mi], fb[ni], acc[mi][ni], 0, 0, 0);
        }

        // Single barrier: drains this iter's copies (pre-hidden by compute)
        // and guards the buffer swap.
        __syncthreads();
        cur ^= 1;
    }

    // Epilogue. C/D layout (m89/m91): col = lane&15, row = (lane>>4)*4 + r.
    const int er = (lane >> 4) * 4;
    const int ec = lane & 15;
    float wh[4];
    #pragma unroll
    for (int ni = 0; ni < 4; ++ni) {
        const int col = n0 + wc * 64 + ni * 16 + ec;
        wh[ni] = 0.5f * (wsqp[col] + wsqp[DOUT + col] +
                         wsqp[2 * DOUT + col] + wsqp[3 * DOUT + col]);
    }
    #pragma unroll
    for (int mi = 0; mi < 4; ++mi) {
        const int row = m0 + wr * 64 + mi * 16 + er;
        #pragma unroll
        for (int r = 0; r < 4; ++r) {
            const float xh = 0.5f * xsq[row + r];
            #pragma unroll
            for (int ni = 0; ni < 4; ++ni) {
                const int col = n0 + wc * 64 + ni * 16 + ec;
                out[(size_t)(row + r) * DOUT + col] = acc[mi][ni][r] - xh - wh[ni];
            }
        }
    }
}

// ---------- launch ----------

extern "C" void kernel_launch(void* const* d_in, const int* in_sizes, int n_in,
                              void* d_out, int out_size, void* d_ws, size_t ws_size,
                              hipStream_t stream) {
    const float* x = (const float*)d_in[0];
    const float* W = (const float*)d_in[1];
    float* out = (float*)d_out;

    // Workspace layout (~12.1 MiB):
    //   [0, 4MiB)             xb   : bf16 x   [2048][1024]
    //   [4MiB, 12MiB)         wbt  : bf16 W^T [4096][1024]
    //   [12MiB, +8KiB)        xsq  : f32 [2048]
    //   [12MiB+32KiB, +64KiB) wsqp : f32 [4][4096] K-partial col sums
    char* ws = (char*)d_ws;
    ushort* xb   = (ushort*)ws;
    ushort* wbt  = (ushort*)(ws + (4u << 20));
    float*  xsq  = (float*)(ws + (12u << 20));
    float*  wsqp = (float*)(ws + (12u << 20) + (32u << 10));

    prep_fused<<<384, 256, 0, stream>>>(x, W, xb, xsq, wbt, wsqp);
    gemm_bt_epi<<<512, 256, 0, stream>>>(xb, wbt, xsq, wsqp, out);
}